// Round 13
// baseline (194.591 us; speedup 1.0000x reference)
//
#include <hip/hip_runtime.h>

typedef float v2f __attribute__((ext_vector_type(2)));
typedef __fp16 h2v __attribute__((ext_vector_type(2)));  // cvt_pkrtz's return type

#define NW 64
#define MAX_EVALS 8
#define FREEZE_TOL 7e-3f
// Freeze fires AFTER the step is applied; frozen lanes are superlinear-path,
// post-step residual ~ kappa*st*e_prev << st. absmax pinned at 3.9e-3 (=2^-8,
// bf16-compare quantum) across tol 1e-3..7e-3 and fp16 storage.

// COORD-PAIR structure (round 13): thread t owns coords (2t, 2t+1). One 8-B
// float2 load per worker row serves both coords; v[w] = packed fp16
// (coordA_w, coordB_w) -> 64 VGPR for 2 coords' data. Every v2f eval op
// computes both coords (the .x/.y slots are coords, not workers): per-coord
// loads, addressing, solve, cvt overhead, and wave count all halve.
// (256,4): live ~110 vs cap 128 -- the margin round 9 validated (112).
// Round-8 spill signature: VGPR<60 / FETCH>>262MB -> revert.
__global__ __launch_bounds__(256, 4) void damed_median_kernel(
    const float* __restrict__ y, float* __restrict__ out, int D) {
  const int t = blockIdx.x * blockDim.x + threadIdx.x;
  const int d0 = 2 * t;
  if (d0 >= D) return;  // D = 2^21 is even -> d0+1 < D whenever d0 < D

  // 64 workers; per worker one coalesced 8B load (wave: 512B contiguous/row),
  // f32 min/max/sum per coord (component-wise), pack to fp16 for residency.
  h2v v[NW];
  v2f vmin = {3.4e38f, 3.4e38f}, vmax = {-3.4e38f, -3.4e38f}, sum2 = {0.f, 0.f};
#pragma unroll
  for (int w = 0; w < NW; ++w) {
    v2f g = *reinterpret_cast<const v2f*>(y + (size_t)w * (size_t)D + (size_t)d0);
    v[w] = __builtin_amdgcn_cvt_pkrtz(g.x, g.y);  // (coordA_w, coordB_w)
    vmin = __builtin_elementwise_min(vmin, g);
    vmax = __builtin_elementwise_max(vmax, g);
    sum2 += g;
  }
  // Per-coord bracket + mean start (components ARE the coords; no fold).
  v2f xl2 = vmin, xg2 = vmax;
  v2f x2 = sum2 * (1.0f / NW);
  x2 = __builtin_elementwise_min(__builtin_elementwise_max(x2, xl2), xg2);

  // A&S 7.1.27: erf(a) = 1 - q(a)^-4, q = 1 + b1 a + b2 a^2 + b3 a^3 + b4 a^4,
  // |err| <= 5e-4, no exp. Derivative of the approx: 4 q^-5 q'(a), used ONCE
  // (eval A); later evals use the free secant slope.
  const float B1 = 0.278393f, B2 = 0.230389f, B3 = 0.000972f, B4 = 0.078108f;
  const v2f one2 = {1.f, 1.f};
  const v2f Q1 = {B1, B1}, Q2 = {B2, B2}, Q3 = {B3, B3}, Q4 = {B4, B4};
  const v2f P1 = {B1, B1}, P2 = {2 * B2, 2 * B2};
  const v2f P3 = {3 * B3, 3 * B3}, P4 = {4 * B4, 4 * B4};

  auto up = [](h2v h) -> v2f {
    v2f r; r.x = (float)h.x; r.y = (float)h.y; return r;
  };

  // Value-only eval for both coords: fm.x = sum_w erf(A_w - xc.x), fm.y same
  // for B. 4-way split accumulator chains across workers.
  auto evalF = [&](v2f xc) -> v2f {
    v2f f0 = {0.f, 0.f}, f1 = {0.f, 0.f}, f2 = {0.f, 0.f}, f3 = {0.f, 0.f};
#pragma unroll
    for (int w = 0; w < NW; w += 4) {
#pragma unroll
      for (int j = 0; j < 4; ++j) {
        v2f tt = up(v[w + j]) - xc;
        v2f aa = __builtin_elementwise_max(tt, -tt);
        v2f qq = __builtin_elementwise_fma(aa, Q4, Q3);
        qq = __builtin_elementwise_fma(aa, qq, Q2);
        qq = __builtin_elementwise_fma(aa, qq, Q1);
        qq = __builtin_elementwise_fma(aa, qq, one2);
        v2f rr;
        rr.x = __builtin_amdgcn_rcpf(qq.x); rr.y = __builtin_amdgcn_rcpf(qq.y);
        rr = rr * rr;   // q^-2
        rr = rr * rr;   // q^-4
        v2f ee = one2 - rr;
        ee.x = __builtin_copysignf(ee.x, tt.x);
        ee.y = __builtin_copysignf(ee.y, tt.y);
        if (j == 0) f0 += ee; else if (j == 1) f1 += ee;
        else if (j == 2) f2 += ee; else f3 += ee;
      }
    }
    return (f0 + f1) + (f2 + f3);
  };

  // ---- eval A: value + analytic derivative -> one true Newton step (both
  // coords in the v2f slots). ----
  v2f fm2, fd2;
  {
    v2f f0 = {0.f, 0.f}, f1 = {0.f, 0.f}, g0 = {0.f, 0.f}, g1 = {0.f, 0.f};
#pragma unroll
    for (int w = 0; w < NW; w += 2) {
#pragma unroll
      for (int j = 0; j < 2; ++j) {
        v2f tt = up(v[w + j]) - x2;
        v2f aa = __builtin_elementwise_max(tt, -tt);
        v2f qq = __builtin_elementwise_fma(aa, Q4, Q3);
        qq = __builtin_elementwise_fma(aa, qq, Q2);
        qq = __builtin_elementwise_fma(aa, qq, Q1);
        qq = __builtin_elementwise_fma(aa, qq, one2);
        v2f dd = __builtin_elementwise_fma(aa, P4, P3);
        dd = __builtin_elementwise_fma(aa, dd, P2);
        dd = __builtin_elementwise_fma(aa, dd, P1);
        v2f rr;
        rr.x = __builtin_amdgcn_rcpf(qq.x); rr.y = __builtin_amdgcn_rcpf(qq.y);
        v2f r2 = rr * rr, r4 = r2 * r2, r5 = r4 * rr;
        v2f ee = one2 - r4;
        ee.x = __builtin_copysignf(ee.x, tt.x);
        ee.y = __builtin_copysignf(ee.y, tt.y);
        if (j == 0) { f0 += ee; g0 = __builtin_elementwise_fma(r5, dd, g0); }
        else        { f1 += ee; g1 = __builtin_elementwise_fma(r5, dd, g1); }
      }
    }
    fm2 = f0 + f1;
    fd2 = (g0 + g1) * 4.0f;  // |f'| of the approx per coord, strictly > 0
  }

  // Per-coord scalar solve state (A = .x, B = .y).
  float xA = x2.x, xB = x2.y;
  float xlA = xl2.x, xgA = xg2.x, xlB = xl2.y, xgB = xg2.y;
  // f decreasing: fm>0 => root above x.
  if (fm2.x > 0.f) xlA = xA; else xgA = xA;
  if (fm2.y > 0.f) xlB = xB; else xgB = xB;
  float xnA = xA + fm2.x * __builtin_amdgcn_rcpf(fd2.x);
  float xnB = xB + fm2.y * __builtin_amdgcn_rcpf(fd2.y);
  // NON-STRICT bracket test (round-1 lesson); NaN fails -> bisect.
  float cA = (xnA >= xlA && xnA <= xgA) ? xnA : 0.5f * (xlA + xgA);
  float cB = (xnB >= xlB && xnB <= xgB) ? xnB : 0.5f * (xlB + xgB);
  bool frzA = (__builtin_fabsf(cA - xA) <= FREEZE_TOL);
  bool frzB = (__builtin_fabsf(cB - xB) <= FREEZE_TOL);
  float xpA = xA, fpA = fm2.x, xpB = xB, fpB = fm2.y;
  xA = cA; xB = cB;

  // ---- secant refinement: slope comes free from (xprev, fmprev). ----
#pragma unroll 1
  for (int e = 1; e < MAX_EVALS; ++e) {
    if (__all(frzA && frzB)) break;  // wave-uniform, deterministic
    v2f fmc = evalF((v2f){xA, xB});
    // coord A
    if (fmc.x > 0.f) xlA = xA; else xgA = xA;
    float xsA = xA + fmc.x * (xA - xpA) / (fpA - fmc.x);
    float ccA = (xsA >= xlA && xsA <= xgA) ? xsA : 0.5f * (xlA + xgA);
    float stA = __builtin_fabsf(ccA - xA);
    bool dnA = (stA <= FREEZE_TOL) || (fmc.x == 0.f);
    float nwA = frzA ? xA : ccA;
    xpA = frzA ? xpA : xA; fpA = frzA ? fpA : fmc.x;
    frzA = frzA || dnA; xA = nwA;
    // coord B
    if (fmc.y > 0.f) xlB = xB; else xgB = xB;
    float xsB = xB + fmc.y * (xB - xpB) / (fpB - fmc.y);
    float ccB = (xsB >= xlB && xsB <= xgB) ? xsB : 0.5f * (xlB + xgB);
    float stB = __builtin_fabsf(ccB - xB);
    bool dnB = (stB <= FREEZE_TOL) || (fmc.y == 0.f);
    float nwB = frzB ? xB : ccB;
    xpB = frzB ? xpB : xB; fpB = frzB ? fpB : fmc.y;
    frzB = frzB || dnB; xB = nwB;
  }
  v2f res; res.x = xA; res.y = xB;
  *reinterpret_cast<v2f*>(out + d0) = res;  // 8B aligned (d0 even)
}

extern "C" void kernel_launch(void* const* d_in, const int* in_sizes, int n_in,
                              void* d_out, int out_size, void* d_ws, size_t ws_size,
                              hipStream_t stream) {
  const float* y = (const float*)d_in[0];
  float* out = (float*)d_out;
  const int D = out_size;          // 2^21 coordinates
  const int threads = 256;         // 2 coords/thread -> 512 coords/block
  const int blocks = (D / 2 + threads - 1) / threads;
  damed_median_kernel<<<blocks, threads, 0, stream>>>(y, out, D);
}

// Round 14
// 118.652 us; speedup vs baseline: 1.6400x; 1.6400x over previous
//
#include <hip/hip_runtime.h>

typedef float v2f __attribute__((ext_vector_type(2)));

#define NW 64
#define NP 32            // worker pairs
#define MAX_EVALS 8
#define FREEZE_TOL 7e-3f
// Freeze fires AFTER the step is applied; frozen lanes are superlinear-path,
// post-step residual ~ kappa*st*e_prev << st. absmax pinned at 3.9e-3 (=2^-8,
// bf16-compare quantum) for tol 1e-3..7e-3 -- tolerance-invariant.

// Round-9 structure restored EXACTLY: (256,4), f32 v[], 1 coord/thread.
// Failed-and-reverted experiments (keep for the record, do not retry):
//   r8  (256,5) cap squeeze   -> full spill: VGPR 32, FETCH 773MB, 3x slower
//   r10 lane-pair worker split -> +shfl/dup solve, 126us
//   r12 fp16 v[] + (256,5)     -> cvt overhead ate the gain, 121us
//   r13 coord-pair per thread  -> live-set blowup, 194us
// This round's only delta vs r9: paired reciprocals -- 2 rcp + 3 pk_mul per
// p-iteration instead of 4 rcp (trans shares the VALU issue port; ~-15%/eval).
__global__ __launch_bounds__(256, 4) void damed_median_kernel(
    const float* __restrict__ y, float* __restrict__ out, int D) {
  int d = blockIdx.x * blockDim.x + threadIdx.x;
  if (d >= D) return;

  // 64 worker values as 32 register pairs (VOP3P operands).
  // y[w][d]: stride-D across w, coalesced across lanes in d.
  v2f v[NP];
  v2f vmin = {3.4e38f, 3.4e38f}, vmax = {-3.4e38f, -3.4e38f}, sum2 = {0.f, 0.f};
#pragma unroll
  for (int p = 0; p < NP; ++p) {
    v2f t;
    t.x = y[(size_t)(2 * p) * (size_t)D + (size_t)d];
    t.y = y[(size_t)(2 * p + 1) * (size_t)D + (size_t)d];
    v[p] = t;
    vmin = __builtin_elementwise_min(vmin, t);
    vmax = __builtin_elementwise_max(vmax, t);
    sum2 += t;
  }
  float xl = fminf(vmin.x, vmin.y);
  float xg = fmaxf(vmax.x, vmax.y);
  float x = (sum2.x + sum2.y) * (1.0f / NW);
  x = fminf(fmaxf(x, xl), xg);

  // A&S 7.1.27: erf(a) = 1 - q(a)^-4, q = 1 + b1 a + b2 a^2 + b3 a^3 + b4 a^4,
  // |err| <= 5e-4, no exp. Derivative of the approx: 4 q^-5 q'(a), used ONCE
  // (eval A); later evals use the free secant slope.
  const float B1 = 0.278393f, B2 = 0.230389f, B3 = 0.000972f, B4 = 0.078108f;
  const v2f one2 = {1.f, 1.f};
  const v2f Q1 = {B1, B1}, Q2 = {B2, B2}, Q3 = {B3, B3}, Q4 = {B4, B4};
  const v2f P1 = {B1, B1}, P2 = {2 * B2, 2 * B2};
  const v2f P3 = {3 * B3, 3 * B3}, P4 = {4 * B4, 4 * B4};

  // Value-only eval: fm(xc) = sum_w erf(v_w - xc); 2x2-way split chains.
  // Paired reciprocals: 1/qA = rcp(qA*qB)*qB, 1/qB = rcp(qA*qB)*qA.
  // q in [1, ~1e3] -> product <= ~1e6, no overflow; +1e-7 rel err, invisible.
  auto evalF = [&](float xc) -> float {
    v2f fmA = {0.f, 0.f}, fmB = {0.f, 0.f};
    v2f nx = {-xc, -xc};
#pragma unroll
    for (int p = 0; p < NP; p += 2) {
      v2f tA = v[p] + nx;
      v2f tB = v[p + 1] + nx;
      v2f aA = __builtin_elementwise_max(tA, -tA);
      v2f aB = __builtin_elementwise_max(tB, -tB);
      v2f qA = __builtin_elementwise_fma(aA, Q4, Q3);
      v2f qB = __builtin_elementwise_fma(aB, Q4, Q3);
      qA = __builtin_elementwise_fma(aA, qA, Q2);
      qB = __builtin_elementwise_fma(aB, qB, Q2);
      qA = __builtin_elementwise_fma(aA, qA, Q1);
      qB = __builtin_elementwise_fma(aB, qB, Q1);
      qA = __builtin_elementwise_fma(aA, qA, one2);
      qB = __builtin_elementwise_fma(aB, qB, one2);
      v2f m = qA * qB;
      v2f r;
      r.x = __builtin_amdgcn_rcpf(m.x); r.y = __builtin_amdgcn_rcpf(m.y);
      v2f rA = r * qB;              // 1/qA
      v2f rB = r * qA;              // 1/qB
      rA = rA * rA; rB = rB * rB;   // q^-2
      rA = rA * rA; rB = rB * rB;   // q^-4
      v2f eA = one2 - rA;
      v2f eB = one2 - rB;
      eA.x = __builtin_copysignf(eA.x, tA.x); eA.y = __builtin_copysignf(eA.y, tA.y);
      eB.x = __builtin_copysignf(eB.x, tB.x); eB.y = __builtin_copysignf(eB.y, tB.y);
      fmA += eA; fmB += eB;
    }
    v2f s = fmA + fmB;
    return s.x + s.y;
  };

  // ---- eval A: value + analytic derivative -> one true Newton step. ----
  float fm0, fd0;
  {
    v2f fmA = {0.f, 0.f}, fmB = {0.f, 0.f}, fdA = {0.f, 0.f}, fdB = {0.f, 0.f};
    v2f nx = {-x, -x};
#pragma unroll
    for (int p = 0; p < NP; p += 2) {
      v2f tA = v[p] + nx;
      v2f tB = v[p + 1] + nx;
      v2f aA = __builtin_elementwise_max(tA, -tA);
      v2f aB = __builtin_elementwise_max(tB, -tB);
      v2f qA = __builtin_elementwise_fma(aA, Q4, Q3);
      v2f qB = __builtin_elementwise_fma(aB, Q4, Q3);
      qA = __builtin_elementwise_fma(aA, qA, Q2);
      qB = __builtin_elementwise_fma(aB, qB, Q2);
      qA = __builtin_elementwise_fma(aA, qA, Q1);
      qB = __builtin_elementwise_fma(aB, qB, Q1);
      qA = __builtin_elementwise_fma(aA, qA, one2);
      qB = __builtin_elementwise_fma(aB, qB, one2);
      v2f dA = __builtin_elementwise_fma(aA, P4, P3);
      v2f dB = __builtin_elementwise_fma(aB, P4, P3);
      dA = __builtin_elementwise_fma(aA, dA, P2);
      dB = __builtin_elementwise_fma(aB, dB, P2);
      dA = __builtin_elementwise_fma(aA, dA, P1);
      dB = __builtin_elementwise_fma(aB, dB, P1);
      v2f m = qA * qB;
      v2f r;
      r.x = __builtin_amdgcn_rcpf(m.x); r.y = __builtin_amdgcn_rcpf(m.y);
      v2f rA = r * qB;              // 1/qA
      v2f rB = r * qA;              // 1/qB
      v2f r2A = rA * rA, r2B = rB * rB;
      v2f r4A = r2A * r2A, r4B = r2B * r2B;
      v2f r5A = r4A * rA, r5B = r4B * rB;
      fdA = __builtin_elementwise_fma(r5A, dA, fdA);
      fdB = __builtin_elementwise_fma(r5B, dB, fdB);
      v2f eA = one2 - r4A;
      v2f eB = one2 - r4B;
      eA.x = __builtin_copysignf(eA.x, tA.x); eA.y = __builtin_copysignf(eA.y, tA.y);
      eB.x = __builtin_copysignf(eB.x, tB.x); eB.y = __builtin_copysignf(eB.y, tB.y);
      fmA += eA; fmB += eB;
    }
    v2f fm2 = fmA + fmB, fd2 = fdA + fdB;
    fm0 = fm2.x + fm2.y;
    fd0 = 4.0f * (fd2.x + fd2.y);  // |f'| of the approx, strictly > 0
  }
  // f decreasing: fm>0 => root above x.
  if (fm0 > 0.f) xl = x; else xg = x;
  float xn = x + fm0 * __builtin_amdgcn_rcpf(fd0);
  bool ok = (xn >= xl) && (xn <= xg);  // non-strict (round-1 lesson); NaN->bisect
  float cand = ok ? xn : 0.5f * (xl + xg);
  bool frozen = (__builtin_fabsf(cand - x) <= FREEZE_TOL);
  float xprev = x, fmprev = fm0;
  x = cand;

  // ---- secant refinement: derivative comes free from (xprev, fmprev). ----
#pragma unroll 1
  for (int e = 1; e < MAX_EVALS; ++e) {
    if (__all(frozen)) break;  // wave-uniform, deterministic for fixed input
    float fmc = evalF(x);
    if (fmc > 0.f) xl = x; else xg = x;
    float xs = x + fmc * (x - xprev) / (fmprev - fmc);  // secant step
    bool ok2 = (xs >= xl) && (xs <= xg);                // NaN/flat -> bisect
    float cand2 = ok2 ? xs : 0.5f * (xl + xg);
    float st = __builtin_fabsf(cand2 - x);
    // fmc==0: x IS the root; freeze (guards exact-zero -> 0/0 -> midpoint hop).
    bool done = (st <= FREEZE_TOL) || (fmc == 0.f);
    float xnew = frozen ? x : cand2;   // frozen lanes do not move
    xprev = frozen ? xprev : x;
    fmprev = frozen ? fmprev : fmc;
    frozen = frozen || done;
    x = xnew;
  }
  out[d] = x;
}

extern "C" void kernel_launch(void* const* d_in, const int* in_sizes, int n_in,
                              void* d_out, int out_size, void* d_ws, size_t ws_size,
                              hipStream_t stream) {
  const float* y = (const float*)d_in[0];
  float* out = (float*)d_out;
  const int D = out_size;  // 2^21 coordinates
  const int threads = 256;
  const int blocks = (D + threads - 1) / threads;
  damed_median_kernel<<<blocks, threads, 0, stream>>>(y, out, D);
}